// Round 8
// baseline (526.846 us; speedup 1.0000x reference)
//
#include <hip/hip_runtime.h>
#include <hip/hip_bf16.h>

#define BN_EPS 1e-5f
#define BINSHIFT 6
#define BINW 64
#define NBLK 256   // chunks for the contention-free counting sort

// ===========================================================================
// Preprocessing: contention-free counting sort by bin = dst>>6, carrying the
// edge_attr payload through the sort (frontier-cursor writes stay L2-resident,
// so no random gather is ever needed). Then per-bin fine sort to node
// granularity — fully streaming / bin-local.
// ===========================================================================

__global__ __launch_bounds__(256)
void hist2d_kernel(const int* __restrict__ dst, int* __restrict__ histmat,
                   int E, int nbins, int chunk) {
    __shared__ int h[2048];
    for (int i = threadIdx.x; i < nbins; i += 256) h[i] = 0;
    __syncthreads();
    int b = blockIdx.x;
    int e0 = b * chunk;
    int e1 = min(E, e0 + chunk);
    for (int e = e0 + threadIdx.x; e < e1; e += 256)
        atomicAdd(&h[dst[e] >> BINSHIFT], 1);
    __syncthreads();
    int* row = histmat + (size_t)b * nbins;
    for (int i = threadIdx.x; i < nbins; i += 256) row[i] = h[i];
}

__global__ __launch_bounds__(256)
void colsum_kernel(const int* __restrict__ histmat, int* __restrict__ bincnt,
                   int nbins) {
    int bin = blockIdx.x * 256 + threadIdx.x;
    if (bin >= nbins) return;
    int s = 0;
    for (int r = 0; r < NBLK; ++r) s += histmat[(size_t)r * nbins + bin];
    bincnt[bin] = s;
}

__global__ __launch_bounds__(1024)
void bin_scan_kernel(const int* __restrict__ bincnt, int* __restrict__ binstart,
                     int nbins, int E) {
    __shared__ int a[2048];
    __shared__ int b[1024];
    int t = threadIdx.x;
    a[t]        = (t < nbins) ? bincnt[t] : 0;
    a[t + 1024] = (t + 1024 < nbins) ? bincnt[t + 1024] : 0;
    __syncthreads();
    b[t] = a[2 * t] + a[2 * t + 1];
    __syncthreads();
    for (int off = 1; off < 1024; off <<= 1) {
        int v = (t >= off) ? b[t - off] : 0;
        __syncthreads();
        b[t] += v;
        __syncthreads();
    }
    int base = (t == 0) ? 0 : b[t - 1];
    if (2 * t < nbins)     binstart[2 * t]     = base;
    if (2 * t + 1 < nbins) binstart[2 * t + 1] = base + a[2 * t];
    if (t == 0) binstart[nbins] = E;
}

__global__ __launch_bounds__(256)
void rowscan_kernel(int* __restrict__ histmat, const int* __restrict__ binstart,
                    int nbins) {
    __shared__ int a[NBLK];
    int b = blockIdx.x;
    int t = threadIdx.x;
    int v = histmat[(size_t)t * nbins + b];
    a[t] = v;
    __syncthreads();
    for (int off = 1; off < NBLK; off <<= 1) {
        int add = (t >= off) ? a[t - off] : 0;
        __syncthreads();
        a[t] += add;
        __syncthreads();
    }
    histmat[(size_t)t * nbins + b] = binstart[b] + a[t] - v;
}

// Placement with ea payload carried along. Reads are streaming; writes go
// through per-bin frontier cursors (active line set ~1563 bins x 1-2 lines
// for meta + ea each => L2-resident, no write amplification).
__global__ __launch_bounds__(256)
void place_kernel(const int* __restrict__ src, const int* __restrict__ dst,
                  const float* __restrict__ edge_attr,
                  const int* __restrict__ histmat,
                  int* __restrict__ tmp_meta, float* __restrict__ tmp_ea,
                  int E, int nbins, int chunk) {
    __shared__ int cur[2048];
    int b = blockIdx.x;
    const int* row = histmat + (size_t)b * nbins;
    for (int i = threadIdx.x; i < nbins; i += 256) cur[i] = row[i];
    __syncthreads();
    int e0 = b * chunk;
    int e1 = min(E, e0 + chunk);
    for (int e = e0 + threadIdx.x; e < e1; e += 256) {
        int d = dst[e];
        int bin = d >> BINSHIFT;
        int pos = atomicAdd(&cur[bin], 1);   // LDS atomic, few per thread
        tmp_meta[pos] = ((d & (BINW - 1)) << 20) | src[e];  // src < 2^20
        const float4* sp = (const float4*)(edge_attr + (size_t)e * 8);
        float4 a0 = sp[0], a1 = sp[1];
        float4* dp = (float4*)(tmp_ea + (size_t)pos * 8);
        dp[0] = a0;
        dp[1] = a1;
    }
}

// Per-bin fine sort to node granularity. All reads sequential, all writes
// bin-local (L2-resident). No random gathers anywhere.
__global__ __launch_bounds__(256)
void pass2_kernel(const int* __restrict__ binstart, const int* __restrict__ tmp_meta,
                  const float* __restrict__ tmp_ea,
                  int* __restrict__ rowstart, int* __restrict__ src_sorted,
                  float* __restrict__ ea_sorted, int N, int E) {
    __shared__ int s_cur[BINW];
    int b = blockIdx.x;
    int node0 = b << BINSHIFT;
    int e0 = binstart[b], e1 = binstart[b + 1];
    int t = threadIdx.x;

    if (t < BINW) s_cur[t] = 0;
    __syncthreads();

    for (int e = e0 + t; e < e1; e += 256)
        atomicAdd(&s_cur[tmp_meta[e] >> 20], 1);
    __syncthreads();

    if (t < BINW) {
        int val = s_cur[t];
        int inc = val;
#pragma unroll
        for (int off = 1; off < 64; off <<= 1) {
            int n = __shfl_up(inc, off);
            if (t >= off) inc += n;
        }
        int excl = e0 + inc - val;
        s_cur[t] = excl;
        int node = node0 + t;
        if (node <= N) rowstart[node] = excl;
    }
    __syncthreads();

    for (int e = e0 + t; e < e1; e += 256) {
        int mx = tmp_meta[e];
        int dl   = mx >> 20;
        int srcv = mx & 0xFFFFF;
        int fpos = atomicAdd(&s_cur[dl], 1);
        src_sorted[fpos] = srcv;
        const float4* sp = (const float4*)(tmp_ea + (size_t)e * 8);
        float4 a0 = sp[0], a1 = sp[1];
        float4* dp = (float4*)(ea_sorted + (size_t)fpos * 8);
        dp[0] = a0;
        dp[1] = a1;
    }
}

// ===========================================================================
// Fused GINE layer — WAVE PER NODE, edge-parallel slots, with src-index
// prefetch to break the per-iteration dependent load chain.
// ===========================================================================
template<int DIN, int C, int S>
__global__ __launch_bounds__(256)
void gine_layer_wave(const float* __restrict__ xin,        // [N, DIN]
                     const int*   __restrict__ rowstart,   // [N+1]
                     const int*   __restrict__ src_sorted, // [E]
                     const float* __restrict__ ea_sorted,  // [E, 8]
                     const float* __restrict__ ew, const float* __restrict__ eb,
                     const float* __restrict__ wa, const float* __restrict__ ba,
                     const float* __restrict__ g, const float* __restrict__ be,
                     const float* __restrict__ m, const float* __restrict__ v,
                     const float* __restrict__ wb, const float* __restrict__ bb,
                     float* __restrict__ hout,             // [N, 16]
                     int N) {
    static_assert(C * S == 64 && C * 4 == DIN, "lane layout");
    constexpr int PAD = DIN + 1;

    __shared__ float s_wa[DIN * 16];
    __shared__ float s_wb[256];
    __shared__ float s_ba[16], s_scale[16], s_shift[16], s_bb[16];
    __shared__ float s_s[16 * PAD];
    __shared__ float s_h[16 * 17];

    int t = threadIdx.x;
    for (int idx = t; idx < DIN * 16; idx += 256) s_wa[idx] = wa[idx];
    s_wb[t] = wb[t];
    if (t < 16) {
        s_ba[t] = ba[t];
        float sc = g[t] * rsqrtf(v[t] + BN_EPS);
        s_scale[t] = sc;
        s_shift[t] = be[t] - m[t] * sc;
        s_bb[t] = bb[t];
    }

    int w    = t >> 6;        // wave id (0..3)
    int lane = t & 63;
    int c    = lane / S;      // channel group
    int s    = lane % S;      // edge slot
    int c0   = c * 4;

    float ew_r[8][4];
#pragma unroll
    for (int k = 0; k < 8; ++k) {
        float4 wv = *(const float4*)(ew + k * DIN + c0);
        ew_r[k][0] = wv.x; ew_r[k][1] = wv.y; ew_r[k][2] = wv.z; ew_r[k][3] = wv.w;
    }
    float4 ebv = *(const float4*)(eb + c0);
    float eb_r[4] = {ebv.x, ebv.y, ebv.z, ebv.w};

    int node0 = blockIdx.x * 16;

#pragma unroll
    for (int q = 0; q < 4; ++q) {
        int nl = w * 4 + q;
        int i  = node0 + nl;
        float acc[4] = {0.f, 0.f, 0.f, 0.f};
        if (i < N) {
            int e0 = rowstart[i];
            int e1 = rowstart[i + 1];
            int e  = e0 + s;
            int sv = (e < e1) ? src_sorted[e] : 0;
            for (; e < e1; e += S) {
                int en = e + S;
                int sv_next = (en < e1) ? src_sorted[en] : 0;  // prefetch
                const float4* ep = (const float4*)(ea_sorted + (size_t)e * 8);
                float4 a0 = ep[0], a1 = ep[1];
                float4 xv = *(const float4*)(xin + (size_t)sv * DIN + c0);
                float av[8] = {a0.x, a0.y, a0.z, a0.w, a1.x, a1.y, a1.z, a1.w};
                float xr[4] = {xv.x, xv.y, xv.z, xv.w};
#pragma unroll
                for (int j = 0; j < 4; ++j) {
                    float lin = eb_r[j];
#pragma unroll
                    for (int k = 0; k < 8; ++k) lin = fmaf(av[k], ew_r[k][j], lin);
                    lin += xr[j];
                    acc[j] += (lin > 0.f ? lin : 0.f);
                }
                sv = sv_next;
            }
        }
#pragma unroll
        for (int mask = S >> 1; mask >= 1; mask >>= 1) {
#pragma unroll
            for (int j = 0; j < 4; ++j) acc[j] += __shfl_xor(acc[j], mask);
        }
        if (s == 0 && i < N) {
            float4 xi = *(const float4*)(xin + (size_t)i * DIN + c0);
            s_s[nl * PAD + c0 + 0] = acc[0] + xi.x;
            s_s[nl * PAD + c0 + 1] = acc[1] + xi.y;
            s_s[nl * PAD + c0 + 2] = acc[2] + xi.z;
            s_s[nl * PAD + c0 + 3] = acc[3] + xi.w;
        }
    }
    __syncthreads();

    int nl2 = t >> 4;
    int j   = t & 15;
    float a = s_ba[j];
#pragma unroll
    for (int k = 0; k < DIN; ++k)
        a = fmaf(s_s[nl2 * PAD + k], s_wa[k * 16 + j], a);
    a = a * s_scale[j] + s_shift[j];
    s_h[nl2 * 17 + j] = a > 0.f ? a : 0.f;
    __syncthreads();

    float o = s_bb[j];
#pragma unroll
    for (int k = 0; k < 16; ++k)
        o = fmaf(s_h[nl2 * 17 + k], s_wb[k * 16 + j], o);
    o = o > 0.f ? o : 0.f;
    int i2 = node0 + nl2;
    if (i2 < N) hout[(size_t)i2 * 16 + j] = o;
}

// ===========================================================================
// Head (unchanged)
// ===========================================================================
__global__ __launch_bounds__(256)
void final_kernel(const float* __restrict__ h1, const float* __restrict__ h2,
                  const float* __restrict__ h3,
                  const float* __restrict__ lw1, const float* __restrict__ lb1,
                  const float* __restrict__ lw2, const float* __restrict__ lb2,
                  float* __restrict__ out, int N) {
    constexpr int NPB = 64;
    __shared__ float s_lw1[48 * 64];
    __shared__ float s_lw2[64 * 4];
    __shared__ float s_lb1[64];
    __shared__ float s_lb2[4];
    __shared__ float s_c[NPB][49];

    int t = threadIdx.x;
    for (int idx = t; idx < 48 * 64; idx += 256) s_lw1[idx] = lw1[idx];
    s_lw2[t] = lw2[t];
    if (t < 64) s_lb1[t] = lb1[t];
    if (t < 4) s_lb2[t] = lb2[t];

    int nl = t >> 2;
    int l  = t & 3;
    int i  = blockIdx.x * NPB + nl;

    if (i < N) {
        float4 c1 = ((const float4*)(h1 + (size_t)i * 16))[l];
        float4 c2 = ((const float4*)(h2 + (size_t)i * 16))[l];
        float4 c3 = ((const float4*)(h3 + (size_t)i * 16))[l];
        s_c[nl][l * 4 + 0] = c1.x; s_c[nl][l * 4 + 1] = c1.y;
        s_c[nl][l * 4 + 2] = c1.z; s_c[nl][l * 4 + 3] = c1.w;
        s_c[nl][16 + l * 4 + 0] = c2.x; s_c[nl][16 + l * 4 + 1] = c2.y;
        s_c[nl][16 + l * 4 + 2] = c2.z; s_c[nl][16 + l * 4 + 3] = c2.w;
        s_c[nl][32 + l * 4 + 0] = c3.x; s_c[nl][32 + l * 4 + 1] = c3.y;
        s_c[nl][32 + l * 4 + 2] = c3.z; s_c[nl][32 + l * 4 + 3] = c3.w;
    }
    __syncthreads();

    float o0 = 0.f, o1 = 0.f, o2 = 0.f, o3 = 0.f;
    if (i < N) {
#pragma unroll 4
        for (int jj = 0; jj < 16; ++jj) {
            int j = l * 16 + jj;
            float a = s_lb1[j];
#pragma unroll
            for (int k = 0; k < 48; ++k) a = fmaf(s_c[nl][k], s_lw1[k * 64 + j], a);
            a = a > 0.f ? a : 0.f;
            o0 = fmaf(a, s_lw2[j * 4 + 0], o0);
            o1 = fmaf(a, s_lw2[j * 4 + 1], o1);
            o2 = fmaf(a, s_lw2[j * 4 + 2], o2);
            o3 = fmaf(a, s_lw2[j * 4 + 3], o3);
        }
    }
    o0 += __shfl_xor(o0, 1); o0 += __shfl_xor(o0, 2);
    o1 += __shfl_xor(o1, 1); o1 += __shfl_xor(o1, 2);
    o2 += __shfl_xor(o2, 1); o2 += __shfl_xor(o2, 2);
    o3 += __shfl_xor(o3, 1); o3 += __shfl_xor(o3, 2);
    if (i < N && l == 0) {
        float4 o = {o0 + s_lb2[0], o1 + s_lb2[1], o2 + s_lb2[2], o3 + s_lb2[3]};
        *(float4*)(out + (size_t)i * 4) = o;
    }
}

// ===========================================================================
// Launch
// ===========================================================================
extern "C" void kernel_launch(void* const* d_in, const int* in_sizes, int n_in,
                              void* d_out, int out_size, void* d_ws, size_t ws_size,
                              hipStream_t stream) {
    const float* x  = (const float*)d_in[0];
    const int*   ei = (const int*)d_in[1];
    const float* ea = (const float*)d_in[2];
    const int N = in_sizes[0] / 32;
    const int E = in_sizes[1] / 2;
    const int* srci = ei;
    const int* dsti = ei + E;

    const float* lw1 = (const float*)d_in[33];
    const float* lb1 = (const float*)d_in[34];
    const float* lw2 = (const float*)d_in[35];
    const float* lb2 = (const float*)d_in[36];

    const int nbins = (N + BINW - 1) >> BINSHIFT;   // 1563
    const int chunk = (E + NBLK - 1) / NBLK;        // 6250

    // Workspace layout. tmp_meta/tmp_ea (57.6 MB) alias h1..h3 (19.2 MB):
    // tmp dead after pass2, h first written by gine layer 1.
    char* p = (char*)d_ws;
    int*   binstart   = (int*)p;   p += (size_t)(nbins + 1 + 3) / 4 * 16;
    int*   bincnt     = (int*)p;   p += (size_t)(nbins + 3) / 4 * 16;
    int*   rowstart   = (int*)p;   p += (size_t)(N + 1 + 3) / 4 * 16;
    int*   histmat    = (int*)p;   p += (size_t)NBLK * nbins * 4;
    int*   src_sorted = (int*)p;   p += (size_t)E * 4;
    float* ea_sorted  = (float*)p; p += (size_t)E * 8 * 4;
    char*  u          = p;
    int*   tmp_meta   = (int*)u;                       // E*4
    float* tmp_ea     = (float*)(u + (size_t)E * 4);   // E*32
    float* h1         = (float*)u;
    float* h2         = h1 + (size_t)N * 16;
    float* h3         = h2 + (size_t)N * 16;

    // ---- Contention-free bin sort (ea carried through) + fine sort ----
    hist2d_kernel<<<NBLK, 256, 0, stream>>>(dsti, histmat, E, nbins, chunk);
    colsum_kernel<<<(nbins + 255) / 256, 256, 0, stream>>>(histmat, bincnt, nbins);
    bin_scan_kernel<<<1, 1024, 0, stream>>>(bincnt, binstart, nbins, E);
    rowscan_kernel<<<nbins, NBLK, 0, stream>>>(histmat, binstart, nbins);
    place_kernel<<<NBLK, 256, 0, stream>>>(srci, dsti, ea, histmat,
                                           tmp_meta, tmp_ea, E, nbins, chunk);
    pass2_kernel<<<nbins, 256, 0, stream>>>(binstart, tmp_meta, tmp_ea,
                                            rowstart, src_sorted, ea_sorted,
                                            N, E);

    // ---- Layers (wave-per-node, edge-parallel, src prefetch) ----
    const int lblocks = (N + 15) / 16;
    gine_layer_wave<32, 8, 8><<<lblocks, 256, 0, stream>>>(
        x, rowstart, src_sorted, ea_sorted,
        (const float*)d_in[3], (const float*)d_in[4],
        (const float*)d_in[5], (const float*)d_in[6],
        (const float*)d_in[7], (const float*)d_in[8],
        (const float*)d_in[9], (const float*)d_in[10],
        (const float*)d_in[11], (const float*)d_in[12], h1, N);

    gine_layer_wave<16, 4, 16><<<lblocks, 256, 0, stream>>>(
        h1, rowstart, src_sorted, ea_sorted,
        (const float*)d_in[13], (const float*)d_in[14],
        (const float*)d_in[15], (const float*)d_in[16],
        (const float*)d_in[17], (const float*)d_in[18],
        (const float*)d_in[19], (const float*)d_in[20],
        (const float*)d_in[21], (const float*)d_in[22], h2, N);

    gine_layer_wave<16, 4, 16><<<lblocks, 256, 0, stream>>>(
        h2, rowstart, src_sorted, ea_sorted,
        (const float*)d_in[23], (const float*)d_in[24],
        (const float*)d_in[25], (const float*)d_in[26],
        (const float*)d_in[27], (const float*)d_in[28],
        (const float*)d_in[29], (const float*)d_in[30],
        (const float*)d_in[31], (const float*)d_in[32], h3, N);

    // ---- Head ----
    final_kernel<<<(N + 63) / 64, 256, 0, stream>>>(
        h1, h2, h3, lw1, lb1, lw2, lb2, (float*)d_out, N);
}

// Round 9
// 519.430 us; speedup vs baseline: 1.0143x; 1.0143x over previous
//
#include <hip/hip_runtime.h>
#include <hip/hip_bf16.h>

#define BN_EPS 1e-5f
#define BINSHIFT 6
#define BINW 64
#define NBLK 1024   // chunks for the contention-free counting sort

// ---- bf16 pack/unpack helpers (RN rounding) ----
__device__ __forceinline__ unsigned pk_bf16(float x, float y) {
    unsigned ux = __float_as_uint(x);
    ux += 0x7FFFu + ((ux >> 16) & 1u);
    unsigned uy = __float_as_uint(y);
    uy += 0x7FFFu + ((uy >> 16) & 1u);
    return (ux >> 16) | (uy & 0xFFFF0000u);
}
__device__ __forceinline__ float bf_lo(unsigned u) { return __uint_as_float(u << 16); }
__device__ __forceinline__ float bf_hi(unsigned u) { return __uint_as_float(u & 0xFFFF0000u); }

// XCD-aware chunk swizzle: consecutive chunks (adjacent per-bin sub-regions)
// land on the same XCD so partial write-lines assemble in one L2.
__device__ __forceinline__ int chunk_of(int bid) {
    return ((bid & 7) << 7) | (bid >> 3);   // NBLK = 1024
}

// ===========================================================================
// Preprocessing: contention-free counting sort by bin = dst>>6, carrying
// edge_attr as packed bf16 (16 B/edge). Then per-bin fine sort to node
// granularity — fully streaming / bin-local.
// ===========================================================================

__global__ __launch_bounds__(256)
void hist2d_kernel(const int* __restrict__ dst, int* __restrict__ histmat,
                   int E, int nbins, int chunk) {
    __shared__ int h[2048];
    for (int i = threadIdx.x; i < nbins; i += 256) h[i] = 0;
    __syncthreads();
    int c = chunk_of(blockIdx.x);
    int e0 = c * chunk;
    int e1 = min(E, e0 + chunk);
    for (int e = e0 + threadIdx.x; e < e1; e += 256)
        atomicAdd(&h[dst[e] >> BINSHIFT], 1);
    __syncthreads();
    int* row = histmat + (size_t)c * nbins;
    for (int i = threadIdx.x; i < nbins; i += 256) row[i] = h[i];
}

__global__ __launch_bounds__(256)
void colsum_kernel(const int* __restrict__ histmat, int* __restrict__ bincnt,
                   int nbins) {
    int bin = blockIdx.x * 256 + threadIdx.x;
    if (bin >= nbins) return;
    int s = 0;
#pragma unroll 8
    for (int r = 0; r < NBLK; ++r) s += histmat[(size_t)r * nbins + bin];
    bincnt[bin] = s;
}

__global__ __launch_bounds__(1024)
void bin_scan_kernel(const int* __restrict__ bincnt, int* __restrict__ binstart,
                     int nbins, int E) {
    __shared__ int a[2048];
    __shared__ int b[1024];
    int t = threadIdx.x;
    a[t]        = (t < nbins) ? bincnt[t] : 0;
    a[t + 1024] = (t + 1024 < nbins) ? bincnt[t + 1024] : 0;
    __syncthreads();
    b[t] = a[2 * t] + a[2 * t + 1];
    __syncthreads();
    for (int off = 1; off < 1024; off <<= 1) {
        int v = (t >= off) ? b[t - off] : 0;
        __syncthreads();
        b[t] += v;
        __syncthreads();
    }
    int base = (t == 0) ? 0 : b[t - 1];
    if (2 * t < nbins)     binstart[2 * t]     = base;
    if (2 * t + 1 < nbins) binstart[2 * t + 1] = base + a[2 * t];
    if (t == 0) binstart[nbins] = E;
}

__global__ __launch_bounds__(1024)
void rowscan_kernel(int* __restrict__ histmat, const int* __restrict__ binstart,
                    int nbins) {
    __shared__ int a[NBLK];
    int b = blockIdx.x;   // bin
    int t = threadIdx.x;  // chunk index
    int v = histmat[(size_t)t * nbins + b];
    a[t] = v;
    __syncthreads();
    for (int off = 1; off < NBLK; off <<= 1) {
        int add = (t >= off) ? a[t - off] : 0;
        __syncthreads();
        a[t] += add;
        __syncthreads();
    }
    histmat[(size_t)t * nbins + b] = binstart[b] + a[t] - v;
}

// Placement: meta (4 B) + bf16 ea (16 B) per edge through per-bin frontier
// cursors. 1024 blocks + XCD swizzle -> 4x wave parallelism, L2-assembling
// write lines.
__global__ __launch_bounds__(256)
void place_kernel(const int* __restrict__ src, const int* __restrict__ dst,
                  const float* __restrict__ edge_attr,
                  const int* __restrict__ histmat,
                  int* __restrict__ tmp_meta, uint4* __restrict__ tmp_ea,
                  int E, int nbins, int chunk) {
    __shared__ int cur[2048];
    int c = chunk_of(blockIdx.x);
    const int* row = histmat + (size_t)c * nbins;
    for (int i = threadIdx.x; i < nbins; i += 256) cur[i] = row[i];
    __syncthreads();
    int e0 = c * chunk;
    int e1 = min(E, e0 + chunk);
    for (int e = e0 + threadIdx.x; e < e1; e += 256) {
        int d = dst[e];
        int bin = d >> BINSHIFT;
        int pos = atomicAdd(&cur[bin], 1);   // LDS atomic, ~6/thread
        tmp_meta[pos] = ((d & (BINW - 1)) << 20) | src[e];  // src < 2^20
        const float4* sp = (const float4*)(edge_attr + (size_t)e * 8);
        float4 a0 = sp[0], a1 = sp[1];
        uint4 pkd;
        pkd.x = pk_bf16(a0.x, a0.y);
        pkd.y = pk_bf16(a0.z, a0.w);
        pkd.z = pk_bf16(a1.x, a1.y);
        pkd.w = pk_bf16(a1.z, a1.w);
        tmp_ea[pos] = pkd;
    }
}

// Per-bin fine sort to node granularity. Sequential reads, bin-local writes.
__global__ __launch_bounds__(256)
void pass2_kernel(const int* __restrict__ binstart, const int* __restrict__ tmp_meta,
                  const uint4* __restrict__ tmp_ea,
                  int* __restrict__ rowstart, int* __restrict__ src_sorted,
                  uint4* __restrict__ ea_sorted, int N, int E) {
    __shared__ int s_cur[BINW];
    int b = blockIdx.x;
    int node0 = b << BINSHIFT;
    int e0 = binstart[b], e1 = binstart[b + 1];
    int t = threadIdx.x;

    if (t < BINW) s_cur[t] = 0;
    __syncthreads();

    for (int e = e0 + t; e < e1; e += 256)
        atomicAdd(&s_cur[tmp_meta[e] >> 20], 1);
    __syncthreads();

    if (t < BINW) {
        int val = s_cur[t];
        int inc = val;
#pragma unroll
        for (int off = 1; off < 64; off <<= 1) {
            int n = __shfl_up(inc, off);
            if (t >= off) inc += n;
        }
        int excl = e0 + inc - val;
        s_cur[t] = excl;
        int node = node0 + t;
        if (node <= N) rowstart[node] = excl;
    }
    __syncthreads();

    for (int e = e0 + t; e < e1; e += 256) {
        int mx = tmp_meta[e];
        int dl   = mx >> 20;
        int srcv = mx & 0xFFFFF;
        int fpos = atomicAdd(&s_cur[dl], 1);
        src_sorted[fpos] = srcv;
        ea_sorted[fpos] = tmp_ea[e];
    }
}

// ===========================================================================
// Fused GINE layer — WAVE PER NODE, edge-parallel slots, src prefetch,
// bf16 ea payload (16 B/edge).
// ===========================================================================
template<int DIN, int C, int S>
__global__ __launch_bounds__(256)
void gine_layer_wave(const float* __restrict__ xin,        // [N, DIN]
                     const int*   __restrict__ rowstart,   // [N+1]
                     const int*   __restrict__ src_sorted, // [E]
                     const uint4* __restrict__ ea_sorted,  // [E] bf16x8
                     const float* __restrict__ ew, const float* __restrict__ eb,
                     const float* __restrict__ wa, const float* __restrict__ ba,
                     const float* __restrict__ g, const float* __restrict__ be,
                     const float* __restrict__ m, const float* __restrict__ v,
                     const float* __restrict__ wb, const float* __restrict__ bb,
                     float* __restrict__ hout,             // [N, 16]
                     int N) {
    static_assert(C * S == 64 && C * 4 == DIN, "lane layout");
    constexpr int PAD = DIN + 1;

    __shared__ float s_wa[DIN * 16];
    __shared__ float s_wb[256];
    __shared__ float s_ba[16], s_scale[16], s_shift[16], s_bb[16];
    __shared__ float s_s[16 * PAD];
    __shared__ float s_h[16 * 17];

    int t = threadIdx.x;
    for (int idx = t; idx < DIN * 16; idx += 256) s_wa[idx] = wa[idx];
    s_wb[t] = wb[t];
    if (t < 16) {
        s_ba[t] = ba[t];
        float sc = g[t] * rsqrtf(v[t] + BN_EPS);
        s_scale[t] = sc;
        s_shift[t] = be[t] - m[t] * sc;
        s_bb[t] = bb[t];
    }

    int w    = t >> 6;        // wave id (0..3)
    int lane = t & 63;
    int c    = lane / S;      // channel group
    int s    = lane % S;      // edge slot
    int c0   = c * 4;

    float ew_r[8][4];
#pragma unroll
    for (int k = 0; k < 8; ++k) {
        float4 wv = *(const float4*)(ew + k * DIN + c0);
        ew_r[k][0] = wv.x; ew_r[k][1] = wv.y; ew_r[k][2] = wv.z; ew_r[k][3] = wv.w;
    }
    float4 ebv = *(const float4*)(eb + c0);
    float eb_r[4] = {ebv.x, ebv.y, ebv.z, ebv.w};

    int node0 = blockIdx.x * 16;

#pragma unroll
    for (int q = 0; q < 4; ++q) {
        int nl = w * 4 + q;
        int i  = node0 + nl;
        float acc[4] = {0.f, 0.f, 0.f, 0.f};
        if (i < N) {
            int e0 = rowstart[i];
            int e1 = rowstart[i + 1];
            int e  = e0 + s;
            int sv = (e < e1) ? src_sorted[e] : 0;
            for (; e < e1; e += S) {
                int en = e + S;
                int sv_next = (en < e1) ? src_sorted[en] : 0;  // prefetch
                uint4 ev = ea_sorted[e];
                float4 xv = *(const float4*)(xin + (size_t)sv * DIN + c0);
                float av[8] = {bf_lo(ev.x), bf_hi(ev.x), bf_lo(ev.y), bf_hi(ev.y),
                               bf_lo(ev.z), bf_hi(ev.z), bf_lo(ev.w), bf_hi(ev.w)};
                float xr[4] = {xv.x, xv.y, xv.z, xv.w};
#pragma unroll
                for (int j = 0; j < 4; ++j) {
                    float lin = eb_r[j];
#pragma unroll
                    for (int k = 0; k < 8; ++k) lin = fmaf(av[k], ew_r[k][j], lin);
                    lin += xr[j];
                    acc[j] += (lin > 0.f ? lin : 0.f);
                }
                sv = sv_next;
            }
        }
#pragma unroll
        for (int mask = S >> 1; mask >= 1; mask >>= 1) {
#pragma unroll
            for (int j = 0; j < 4; ++j) acc[j] += __shfl_xor(acc[j], mask);
        }
        if (s == 0 && i < N) {
            float4 xi = *(const float4*)(xin + (size_t)i * DIN + c0);
            s_s[nl * PAD + c0 + 0] = acc[0] + xi.x;
            s_s[nl * PAD + c0 + 1] = acc[1] + xi.y;
            s_s[nl * PAD + c0 + 2] = acc[2] + xi.z;
            s_s[nl * PAD + c0 + 3] = acc[3] + xi.w;
        }
    }
    __syncthreads();

    int nl2 = t >> 4;
    int j   = t & 15;
    float a = s_ba[j];
#pragma unroll
    for (int k = 0; k < DIN; ++k)
        a = fmaf(s_s[nl2 * PAD + k], s_wa[k * 16 + j], a);
    a = a * s_scale[j] + s_shift[j];
    s_h[nl2 * 17 + j] = a > 0.f ? a : 0.f;
    __syncthreads();

    float o = s_bb[j];
#pragma unroll
    for (int k = 0; k < 16; ++k)
        o = fmaf(s_h[nl2 * 17 + k], s_wb[k * 16 + j], o);
    o = o > 0.f ? o : 0.f;
    int i2 = node0 + nl2;
    if (i2 < N) hout[(size_t)i2 * 16 + j] = o;
}

// ===========================================================================
// Head (unchanged)
// ===========================================================================
__global__ __launch_bounds__(256)
void final_kernel(const float* __restrict__ h1, const float* __restrict__ h2,
                  const float* __restrict__ h3,
                  const float* __restrict__ lw1, const float* __restrict__ lb1,
                  const float* __restrict__ lw2, const float* __restrict__ lb2,
                  float* __restrict__ out, int N) {
    constexpr int NPB = 64;
    __shared__ float s_lw1[48 * 64];
    __shared__ float s_lw2[64 * 4];
    __shared__ float s_lb1[64];
    __shared__ float s_lb2[4];
    __shared__ float s_c[NPB][49];

    int t = threadIdx.x;
    for (int idx = t; idx < 48 * 64; idx += 256) s_lw1[idx] = lw1[idx];
    s_lw2[t] = lw2[t];
    if (t < 64) s_lb1[t] = lb1[t];
    if (t < 4) s_lb2[t] = lb2[t];

    int nl = t >> 2;
    int l  = t & 3;
    int i  = blockIdx.x * NPB + nl;

    if (i < N) {
        float4 c1 = ((const float4*)(h1 + (size_t)i * 16))[l];
        float4 c2 = ((const float4*)(h2 + (size_t)i * 16))[l];
        float4 c3 = ((const float4*)(h3 + (size_t)i * 16))[l];
        s_c[nl][l * 4 + 0] = c1.x; s_c[nl][l * 4 + 1] = c1.y;
        s_c[nl][l * 4 + 2] = c1.z; s_c[nl][l * 4 + 3] = c1.w;
        s_c[nl][16 + l * 4 + 0] = c2.x; s_c[nl][16 + l * 4 + 1] = c2.y;
        s_c[nl][16 + l * 4 + 2] = c2.z; s_c[nl][16 + l * 4 + 3] = c2.w;
        s_c[nl][32 + l * 4 + 0] = c3.x; s_c[nl][32 + l * 4 + 1] = c3.y;
        s_c[nl][32 + l * 4 + 2] = c3.z; s_c[nl][32 + l * 4 + 3] = c3.w;
    }
    __syncthreads();

    float o0 = 0.f, o1 = 0.f, o2 = 0.f, o3 = 0.f;
    if (i < N) {
#pragma unroll 4
        for (int jj = 0; jj < 16; ++jj) {
            int j = l * 16 + jj;
            float a = s_lb1[j];
#pragma unroll
            for (int k = 0; k < 48; ++k) a = fmaf(s_c[nl][k], s_lw1[k * 64 + j], a);
            a = a > 0.f ? a : 0.f;
            o0 = fmaf(a, s_lw2[j * 4 + 0], o0);
            o1 = fmaf(a, s_lw2[j * 4 + 1], o1);
            o2 = fmaf(a, s_lw2[j * 4 + 2], o2);
            o3 = fmaf(a, s_lw2[j * 4 + 3], o3);
        }
    }
    o0 += __shfl_xor(o0, 1); o0 += __shfl_xor(o0, 2);
    o1 += __shfl_xor(o1, 1); o1 += __shfl_xor(o1, 2);
    o2 += __shfl_xor(o2, 1); o2 += __shfl_xor(o2, 2);
    o3 += __shfl_xor(o3, 1); o3 += __shfl_xor(o3, 2);
    if (i < N && l == 0) {
        float4 o = {o0 + s_lb2[0], o1 + s_lb2[1], o2 + s_lb2[2], o3 + s_lb2[3]};
        *(float4*)(out + (size_t)i * 4) = o;
    }
}

// ===========================================================================
// Launch
// ===========================================================================
extern "C" void kernel_launch(void* const* d_in, const int* in_sizes, int n_in,
                              void* d_out, int out_size, void* d_ws, size_t ws_size,
                              hipStream_t stream) {
    const float* x  = (const float*)d_in[0];
    const int*   ei = (const int*)d_in[1];
    const float* ea = (const float*)d_in[2];
    const int N = in_sizes[0] / 32;
    const int E = in_sizes[1] / 2;
    const int* srci = ei;
    const int* dsti = ei + E;

    const float* lw1 = (const float*)d_in[33];
    const float* lb1 = (const float*)d_in[34];
    const float* lw2 = (const float*)d_in[35];
    const float* lb2 = (const float*)d_in[36];

    const int nbins = (N + BINW - 1) >> BINSHIFT;   // 1563
    const int chunk = (E + NBLK - 1) / NBLK;        // 1563

    // Workspace layout. tmp_meta/tmp_ea (32 MB) alias h1..h3 (19.2 MB):
    // tmp dead after pass2, h first written by gine layer 1.
    char* p = (char*)d_ws;
    int*   binstart   = (int*)p;   p += (size_t)(nbins + 1 + 3) / 4 * 16;
    int*   bincnt     = (int*)p;   p += (size_t)(nbins + 3) / 4 * 16;
    int*   rowstart   = (int*)p;   p += (size_t)(N + 1 + 3) / 4 * 16;
    int*   histmat    = (int*)p;   p += (size_t)NBLK * nbins * 4;
    int*   src_sorted = (int*)p;   p += (size_t)E * 4;
    uint4* ea_sorted  = (uint4*)p; p += (size_t)E * 16;
    char*  u          = p;
    int*   tmp_meta   = (int*)u;                        // E*4
    uint4* tmp_ea     = (uint4*)(u + (size_t)E * 4);    // E*16
    float* h1         = (float*)u;
    float* h2         = h1 + (size_t)N * 16;
    float* h3         = h2 + (size_t)N * 16;

    // ---- Contention-free bin sort (bf16 ea carried through) + fine sort ----
    hist2d_kernel<<<NBLK, 256, 0, stream>>>(dsti, histmat, E, nbins, chunk);
    colsum_kernel<<<(nbins + 255) / 256, 256, 0, stream>>>(histmat, bincnt, nbins);
    bin_scan_kernel<<<1, 1024, 0, stream>>>(bincnt, binstart, nbins, E);
    rowscan_kernel<<<nbins, NBLK, 0, stream>>>(histmat, binstart, nbins);
    place_kernel<<<NBLK, 256, 0, stream>>>(srci, dsti, ea, histmat,
                                           tmp_meta, tmp_ea, E, nbins, chunk);
    pass2_kernel<<<nbins, 256, 0, stream>>>(binstart, tmp_meta, tmp_ea,
                                            rowstart, src_sorted, ea_sorted,
                                            N, E);

    // ---- Layers (wave-per-node, edge-parallel, bf16 ea) ----
    const int lblocks = (N + 15) / 16;
    gine_layer_wave<32, 8, 8><<<lblocks, 256, 0, stream>>>(
        x, rowstart, src_sorted, ea_sorted,
        (const float*)d_in[3], (const float*)d_in[4],
        (const float*)d_in[5], (const float*)d_in[6],
        (const float*)d_in[7], (const float*)d_in[8],
        (const float*)d_in[9], (const float*)d_in[10],
        (const float*)d_in[11], (const float*)d_in[12], h1, N);

    gine_layer_wave<16, 4, 16><<<lblocks, 256, 0, stream>>>(
        h1, rowstart, src_sorted, ea_sorted,
        (const float*)d_in[13], (const float*)d_in[14],
        (const float*)d_in[15], (const float*)d_in[16],
        (const float*)d_in[17], (const float*)d_in[18],
        (const float*)d_in[19], (const float*)d_in[20],
        (const float*)d_in[21], (const float*)d_in[22], h2, N);

    gine_layer_wave<16, 4, 16><<<lblocks, 256, 0, stream>>>(
        h2, rowstart, src_sorted, ea_sorted,
        (const float*)d_in[23], (const float*)d_in[24],
        (const float*)d_in[25], (const float*)d_in[26],
        (const float*)d_in[27], (const float*)d_in[28],
        (const float*)d_in[29], (const float*)d_in[30],
        (const float*)d_in[31], (const float*)d_in[32], h3, N);

    // ---- Head ----
    final_kernel<<<(N + 63) / 64, 256, 0, stream>>>(
        h1, h2, h3, lw1, lb1, lw2, lb2, (float*)d_out, N);
}

// Round 10
// 503.066 us; speedup vs baseline: 1.0473x; 1.0325x over previous
//
#include <hip/hip_runtime.h>
#include <hip/hip_bf16.h>

#define BN_EPS 1e-5f
#define BINSHIFT 6
#define BINW 64
#define NBLK 1024          // chunks for the contention-free counting sort
#define NSEG 8
#define SEGW (NBLK / NSEG) // 128

// ---- bf16 helpers (RN rounding) ----
__device__ __forceinline__ unsigned pk_bf16(float x, float y) {
    unsigned ux = __float_as_uint(x);
    ux += 0x7FFFu + ((ux >> 16) & 1u);
    unsigned uy = __float_as_uint(y);
    uy += 0x7FFFu + ((uy >> 16) & 1u);
    return (ux >> 16) | (uy & 0xFFFF0000u);
}
__device__ __forceinline__ unsigned short f2bf(float x) {
    unsigned u = __float_as_uint(x);
    u += 0x7FFFu + ((u >> 16) & 1u);
    return (unsigned short)(u >> 16);
}
__device__ __forceinline__ float bfu(unsigned short u) {
    return __uint_as_float((unsigned)u << 16);
}
__device__ __forceinline__ float bf_lo(unsigned u) { return __uint_as_float(u << 16); }
__device__ __forceinline__ float bf_hi(unsigned u) { return __uint_as_float(u & 0xFFFF0000u); }

// XCD-aware chunk swizzle: consecutive chunks land on the same XCD so their
// adjacent write lines (tmp regions, histmatT) assemble in one L2.
__device__ __forceinline__ int chunk_of(int bid) {
    return ((bid & 7) << 7) | (bid >> 3);   // NBLK = 1024
}

// ===========================================================================
// Preprocessing: contention-free counting sort by bin = dst>>6 carrying bf16
// edge_attr. Histogram stored TRANSPOSED [bin][chunk] so the scan reads are
// contiguous; the scan's output bases go back to [chunk][bin] via coalesced
// writes for place to read row-wise.
// ===========================================================================

__global__ __launch_bounds__(256)
void hist2d_kernel(const int* __restrict__ dst, int* __restrict__ histmatT,
                   int E, int nbins, int chunk) {
    __shared__ int h[2048];
    for (int i = threadIdx.x; i < nbins; i += 256) h[i] = 0;
    __syncthreads();
    int c = chunk_of(blockIdx.x);
    int e0 = c * chunk;
    int e1 = min(E, e0 + chunk);
    for (int e = e0 + threadIdx.x; e < e1; e += 256)
        atomicAdd(&h[dst[e] >> BINSHIFT], 1);
    __syncthreads();
    // transposed write: 4B at [bin][c]; same-XCD neighbor chunks share lines
    for (int i = threadIdx.x; i < nbins; i += 256)
        histmatT[(size_t)i * NBLK + c] = h[i];
}

// Per-bin totals + per-segment partials. Thread = bin, contiguous streams.
__global__ __launch_bounds__(256)
void colsum_kernel(const int* __restrict__ histmatT, int* __restrict__ bincnt,
                   int* __restrict__ segsum, int nbins) {
    int bin = blockIdx.x * 256 + threadIdx.x;
    if (bin >= nbins) return;
    const int* col = histmatT + (size_t)bin * NBLK;
    int tot = 0;
#pragma unroll
    for (int s = 0; s < NSEG; ++s) {
        int ps = 0;
#pragma unroll 16
        for (int r = 0; r < SEGW; ++r) ps += col[s * SEGW + r];
        segsum[s * nbins + bin] = ps;
        tot += ps;
    }
    bincnt[bin] = tot;
}

__global__ __launch_bounds__(1024)
void bin_scan_kernel(const int* __restrict__ bincnt, int* __restrict__ binstart,
                     int nbins, int E) {
    __shared__ int a[2048];
    __shared__ int b[1024];
    int t = threadIdx.x;
    a[t]        = (t < nbins) ? bincnt[t] : 0;
    a[t + 1024] = (t + 1024 < nbins) ? bincnt[t + 1024] : 0;
    __syncthreads();
    b[t] = a[2 * t] + a[2 * t + 1];
    __syncthreads();
    for (int off = 1; off < 1024; off <<= 1) {
        int v = (t >= off) ? b[t - off] : 0;
        __syncthreads();
        b[t] += v;
        __syncthreads();
    }
    int base = (t == 0) ? 0 : b[t - 1];
    if (2 * t < nbins)     binstart[2 * t]     = base;
    if (2 * t + 1 < nbins) binstart[2 * t + 1] = base + a[2 * t];
    if (t == 0) binstart[nbins] = E;
}

// Segmented serial scan: thread (bin, seg) streams its contiguous 128-chunk
// slice of histmatT and writes exclusive bases COALESCED into basemat
// [chunk][bin] (the layout place consumes row-wise).
__global__ __launch_bounds__(256)
void rowscan_kernel(const int* __restrict__ histmatT, const int* __restrict__ binstart,
                    const int* __restrict__ segsum, int* __restrict__ basemat,
                    int nbins) {
    int bin = blockIdx.x * 256 + threadIdx.x;
    if (bin >= nbins) return;
    int seg = blockIdx.y;
    int base = binstart[bin];
    for (int s = 0; s < seg; ++s) base += segsum[s * nbins + bin];
    const int* col = histmatT + (size_t)bin * NBLK + seg * SEGW;
#pragma unroll 8
    for (int r = 0; r < SEGW; ++r) {
        int v = col[r];
        basemat[(size_t)(seg * SEGW + r) * nbins + bin] = base;
        base += v;
    }
}

// Placement: meta (4 B) + bf16 ea (16 B) per edge through per-bin frontier
// cursors (LDS); base row read coalesced from basemat.
__global__ __launch_bounds__(256)
void place_kernel(const int* __restrict__ src, const int* __restrict__ dst,
                  const float* __restrict__ edge_attr,
                  const int* __restrict__ basemat,
                  int* __restrict__ tmp_meta, uint4* __restrict__ tmp_ea,
                  int E, int nbins, int chunk) {
    __shared__ int cur[2048];
    int c = chunk_of(blockIdx.x);
    const int* row = basemat + (size_t)c * nbins;
    for (int i = threadIdx.x; i < nbins; i += 256) cur[i] = row[i];
    __syncthreads();
    int e0 = c * chunk;
    int e1 = min(E, e0 + chunk);
    for (int e = e0 + threadIdx.x; e < e1; e += 256) {
        int d = dst[e];
        int bin = d >> BINSHIFT;
        int pos = atomicAdd(&cur[bin], 1);   // LDS atomic, ~6/thread
        tmp_meta[pos] = ((d & (BINW - 1)) << 20) | src[e];  // src < 2^20
        const float4* sp = (const float4*)(edge_attr + (size_t)e * 8);
        float4 a0 = sp[0], a1 = sp[1];
        uint4 pkd;
        pkd.x = pk_bf16(a0.x, a0.y);
        pkd.y = pk_bf16(a0.z, a0.w);
        pkd.z = pk_bf16(a1.x, a1.y);
        pkd.w = pk_bf16(a1.z, a1.w);
        tmp_ea[pos] = pkd;
    }
}

// Per-bin fine sort to node granularity. Sequential reads, bin-local writes.
__global__ __launch_bounds__(256)
void pass2_kernel(const int* __restrict__ binstart, const int* __restrict__ tmp_meta,
                  const uint4* __restrict__ tmp_ea,
                  int* __restrict__ rowstart, int* __restrict__ src_sorted,
                  uint4* __restrict__ ea_sorted, int N, int E) {
    __shared__ int s_cur[BINW];
    int b = blockIdx.x;
    int node0 = b << BINSHIFT;
    int e0 = binstart[b], e1 = binstart[b + 1];
    int t = threadIdx.x;

    if (t < BINW) s_cur[t] = 0;
    __syncthreads();

    for (int e = e0 + t; e < e1; e += 256)
        atomicAdd(&s_cur[tmp_meta[e] >> 20], 1);
    __syncthreads();

    if (t < BINW) {
        int val = s_cur[t];
        int inc = val;
#pragma unroll
        for (int off = 1; off < 64; off <<= 1) {
            int n = __shfl_up(inc, off);
            if (t >= off) inc += n;
        }
        int excl = e0 + inc - val;
        s_cur[t] = excl;
        int node = node0 + t;
        if (node <= N) rowstart[node] = excl;
    }
    __syncthreads();

    for (int e = e0 + t; e < e1; e += 256) {
        int mx = tmp_meta[e];
        int dl   = mx >> 20;
        int srcv = mx & 0xFFFFF;
        int fpos = atomicAdd(&s_cur[dl], 1);
        src_sorted[fpos] = srcv;
        ea_sorted[fpos] = tmp_ea[e];
    }
}

// ===========================================================================
// Fused GINE layer — WAVE PER NODE, edge-parallel slots, src prefetch,
// bf16 ea payload; input either fp32 (layer 1) or bf16 (layers 2/3);
// output bf16.
// ===========================================================================
template<int DIN, int C, int S, bool XBF>
__global__ __launch_bounds__(256)
void gine_layer_wave(const void* __restrict__ xin_,      // [N, DIN] fp32|bf16
                     const int*   __restrict__ rowstart,   // [N+1]
                     const int*   __restrict__ src_sorted, // [E]
                     const uint4* __restrict__ ea_sorted,  // [E] bf16x8
                     const float* __restrict__ ew, const float* __restrict__ eb,
                     const float* __restrict__ wa, const float* __restrict__ ba,
                     const float* __restrict__ g, const float* __restrict__ be,
                     const float* __restrict__ m, const float* __restrict__ v,
                     const float* __restrict__ wb, const float* __restrict__ bb,
                     unsigned short* __restrict__ hout,    // [N, 16] bf16
                     int N) {
    static_assert(C * S == 64 && C * 4 == DIN, "lane layout");
    constexpr int PAD = DIN + 1;
    const float* xf = (const float*)xin_;
    const unsigned short* xb = (const unsigned short*)xin_;

    __shared__ float s_wa[DIN * 16];
    __shared__ float s_wb[256];
    __shared__ float s_ba[16], s_scale[16], s_shift[16], s_bb[16];
    __shared__ float s_s[16 * PAD];
    __shared__ float s_h[16 * 17];

    int t = threadIdx.x;
    for (int idx = t; idx < DIN * 16; idx += 256) s_wa[idx] = wa[idx];
    s_wb[t] = wb[t];
    if (t < 16) {
        s_ba[t] = ba[t];
        float sc = g[t] * rsqrtf(v[t] + BN_EPS);
        s_scale[t] = sc;
        s_shift[t] = be[t] - m[t] * sc;
        s_bb[t] = bb[t];
    }

    int w    = t >> 6;        // wave id (0..3)
    int lane = t & 63;
    int c    = lane / S;      // channel group
    int s    = lane % S;      // edge slot
    int c0   = c * 4;

    float ew_r[8][4];
#pragma unroll
    for (int k = 0; k < 8; ++k) {
        float4 wv = *(const float4*)(ew + k * DIN + c0);
        ew_r[k][0] = wv.x; ew_r[k][1] = wv.y; ew_r[k][2] = wv.z; ew_r[k][3] = wv.w;
    }
    float4 ebv = *(const float4*)(eb + c0);
    float eb_r[4] = {ebv.x, ebv.y, ebv.z, ebv.w};

    int node0 = blockIdx.x * 16;

#pragma unroll
    for (int q = 0; q < 4; ++q) {
        int nl = w * 4 + q;
        int i  = node0 + nl;
        float acc[4] = {0.f, 0.f, 0.f, 0.f};
        if (i < N) {
            int e0 = rowstart[i];
            int e1 = rowstart[i + 1];
            int e  = e0 + s;
            int sv = (e < e1) ? src_sorted[e] : 0;
            for (; e < e1; e += S) {
                int en = e + S;
                int sv_next = (en < e1) ? src_sorted[en] : 0;  // prefetch
                uint4 ev = ea_sorted[e];
                float xr[4];
                if constexpr (XBF) {
                    ushort4 xv = *(const ushort4*)(xb + (size_t)sv * DIN + c0);
                    xr[0] = bfu(xv.x); xr[1] = bfu(xv.y);
                    xr[2] = bfu(xv.z); xr[3] = bfu(xv.w);
                } else {
                    float4 xv = *(const float4*)(xf + (size_t)sv * DIN + c0);
                    xr[0] = xv.x; xr[1] = xv.y; xr[2] = xv.z; xr[3] = xv.w;
                }
                float av[8] = {bf_lo(ev.x), bf_hi(ev.x), bf_lo(ev.y), bf_hi(ev.y),
                               bf_lo(ev.z), bf_hi(ev.z), bf_lo(ev.w), bf_hi(ev.w)};
#pragma unroll
                for (int j = 0; j < 4; ++j) {
                    float lin = eb_r[j];
#pragma unroll
                    for (int k = 0; k < 8; ++k) lin = fmaf(av[k], ew_r[k][j], lin);
                    lin += xr[j];
                    acc[j] += (lin > 0.f ? lin : 0.f);
                }
                sv = sv_next;
            }
        }
#pragma unroll
        for (int mask = S >> 1; mask >= 1; mask >>= 1) {
#pragma unroll
            for (int j = 0; j < 4; ++j) acc[j] += __shfl_xor(acc[j], mask);
        }
        if (s == 0 && i < N) {
            float xi[4];
            if constexpr (XBF) {
                ushort4 xv = *(const ushort4*)(xb + (size_t)i * DIN + c0);
                xi[0] = bfu(xv.x); xi[1] = bfu(xv.y);
                xi[2] = bfu(xv.z); xi[3] = bfu(xv.w);
            } else {
                float4 xv = *(const float4*)(xf + (size_t)i * DIN + c0);
                xi[0] = xv.x; xi[1] = xv.y; xi[2] = xv.z; xi[3] = xv.w;
            }
            s_s[nl * PAD + c0 + 0] = acc[0] + xi[0];
            s_s[nl * PAD + c0 + 1] = acc[1] + xi[1];
            s_s[nl * PAD + c0 + 2] = acc[2] + xi[2];
            s_s[nl * PAD + c0 + 3] = acc[3] + xi[3];
        }
    }
    __syncthreads();

    int nl2 = t >> 4;
    int j   = t & 15;
    float a = s_ba[j];
#pragma unroll
    for (int k = 0; k < DIN; ++k)
        a = fmaf(s_s[nl2 * PAD + k], s_wa[k * 16 + j], a);
    a = a * s_scale[j] + s_shift[j];
    s_h[nl2 * 17 + j] = a > 0.f ? a : 0.f;
    __syncthreads();

    float o = s_bb[j];
#pragma unroll
    for (int k = 0; k < 16; ++k)
        o = fmaf(s_h[nl2 * 17 + k], s_wb[k * 16 + j], o);
    o = o > 0.f ? o : 0.f;
    int i2 = node0 + nl2;
    if (i2 < N) hout[(size_t)i2 * 16 + j] = f2bf(o);  // coalesced 2B stores
}

// ===========================================================================
// Head: bf16 h inputs.
// ===========================================================================
__global__ __launch_bounds__(256)
void final_kernel(const unsigned short* __restrict__ h1,
                  const unsigned short* __restrict__ h2,
                  const unsigned short* __restrict__ h3,
                  const float* __restrict__ lw1, const float* __restrict__ lb1,
                  const float* __restrict__ lw2, const float* __restrict__ lb2,
                  float* __restrict__ out, int N) {
    constexpr int NPB = 64;
    __shared__ float s_lw1[48 * 64];
    __shared__ float s_lw2[64 * 4];
    __shared__ float s_lb1[64];
    __shared__ float s_lb2[4];
    __shared__ float s_c[NPB][49];

    int t = threadIdx.x;
    for (int idx = t; idx < 48 * 64; idx += 256) s_lw1[idx] = lw1[idx];
    s_lw2[t] = lw2[t];
    if (t < 64) s_lb1[t] = lb1[t];
    if (t < 4) s_lb2[t] = lb2[t];

    int nl = t >> 2;
    int l  = t & 3;
    int i  = blockIdx.x * NPB + nl;

    if (i < N) {
        ushort4 c1 = *(const ushort4*)(h1 + (size_t)i * 16 + l * 4);
        ushort4 c2 = *(const ushort4*)(h2 + (size_t)i * 16 + l * 4);
        ushort4 c3 = *(const ushort4*)(h3 + (size_t)i * 16 + l * 4);
        s_c[nl][l * 4 + 0] = bfu(c1.x); s_c[nl][l * 4 + 1] = bfu(c1.y);
        s_c[nl][l * 4 + 2] = bfu(c1.z); s_c[nl][l * 4 + 3] = bfu(c1.w);
        s_c[nl][16 + l * 4 + 0] = bfu(c2.x); s_c[nl][16 + l * 4 + 1] = bfu(c2.y);
        s_c[nl][16 + l * 4 + 2] = bfu(c2.z); s_c[nl][16 + l * 4 + 3] = bfu(c2.w);
        s_c[nl][32 + l * 4 + 0] = bfu(c3.x); s_c[nl][32 + l * 4 + 1] = bfu(c3.y);
        s_c[nl][32 + l * 4 + 2] = bfu(c3.z); s_c[nl][32 + l * 4 + 3] = bfu(c3.w);
    }
    __syncthreads();

    float o0 = 0.f, o1 = 0.f, o2 = 0.f, o3 = 0.f;
    if (i < N) {
#pragma unroll 4
        for (int jj = 0; jj < 16; ++jj) {
            int j = l * 16 + jj;
            float a = s_lb1[j];
#pragma unroll
            for (int k = 0; k < 48; ++k) a = fmaf(s_c[nl][k], s_lw1[k * 64 + j], a);
            a = a > 0.f ? a : 0.f;
            o0 = fmaf(a, s_lw2[j * 4 + 0], o0);
            o1 = fmaf(a, s_lw2[j * 4 + 1], o1);
            o2 = fmaf(a, s_lw2[j * 4 + 2], o2);
            o3 = fmaf(a, s_lw2[j * 4 + 3], o3);
        }
    }
    o0 += __shfl_xor(o0, 1); o0 += __shfl_xor(o0, 2);
    o1 += __shfl_xor(o1, 1); o1 += __shfl_xor(o1, 2);
    o2 += __shfl_xor(o2, 1); o2 += __shfl_xor(o2, 2);
    o3 += __shfl_xor(o3, 1); o3 += __shfl_xor(o3, 2);
    if (i < N && l == 0) {
        float4 o = {o0 + s_lb2[0], o1 + s_lb2[1], o2 + s_lb2[2], o3 + s_lb2[3]};
        *(float4*)(out + (size_t)i * 4) = o;
    }
}

// ===========================================================================
// Launch
// ===========================================================================
extern "C" void kernel_launch(void* const* d_in, const int* in_sizes, int n_in,
                              void* d_out, int out_size, void* d_ws, size_t ws_size,
                              hipStream_t stream) {
    const float* x  = (const float*)d_in[0];
    const int*   ei = (const int*)d_in[1];
    const float* ea = (const float*)d_in[2];
    const int N = in_sizes[0] / 32;
    const int E = in_sizes[1] / 2;
    const int* srci = ei;
    const int* dsti = ei + E;

    const float* lw1 = (const float*)d_in[33];
    const float* lb1 = (const float*)d_in[34];
    const float* lw2 = (const float*)d_in[35];
    const float* lb2 = (const float*)d_in[36];

    const int nbins = (N + BINW - 1) >> BINSHIFT;   // 1563
    const int chunk = (E + NBLK - 1) / NBLK;        // 1563

    // Workspace. tmp_meta/tmp_ea (32 MB) alias h1..h3 (bf16, 9.6 MB total):
    // tmp dead after pass2, h first written by gine layer 1.
    char* p = (char*)d_ws;
    int*   binstart   = (int*)p;   p += (size_t)(nbins + 1 + 3) / 4 * 16;
    int*   bincnt     = (int*)p;   p += (size_t)(nbins + 3) / 4 * 16;
    int*   segsum     = (int*)p;   p += (size_t)(NSEG * nbins + 3) / 4 * 16;
    int*   rowstart   = (int*)p;   p += (size_t)(N + 1 + 3) / 4 * 16;
    int*   histmatT   = (int*)p;   p += (size_t)NBLK * nbins * 4;
    int*   basemat    = (int*)p;   p += (size_t)NBLK * nbins * 4;
    int*   src_sorted = (int*)p;   p += (size_t)E * 4;
    uint4* ea_sorted  = (uint4*)p; p += (size_t)E * 16;
    char*  u          = p;
    int*   tmp_meta   = (int*)u;                        // E*4
    uint4* tmp_ea     = (uint4*)(u + (size_t)E * 4);    // E*16
    unsigned short* h1 = (unsigned short*)u;            // N*16*2 each
    unsigned short* h2 = h1 + (size_t)N * 16;
    unsigned short* h3 = h2 + (size_t)N * 16;

    // ---- Contention-free bin sort (transposed-scan) + fine sort ----
    hist2d_kernel<<<NBLK, 256, 0, stream>>>(dsti, histmatT, E, nbins, chunk);
    colsum_kernel<<<(nbins + 255) / 256, 256, 0, stream>>>(histmatT, bincnt,
                                                           segsum, nbins);
    bin_scan_kernel<<<1, 1024, 0, stream>>>(bincnt, binstart, nbins, E);
    rowscan_kernel<<<dim3((nbins + 255) / 256, NSEG), 256, 0, stream>>>(
        histmatT, binstart, segsum, basemat, nbins);
    place_kernel<<<NBLK, 256, 0, stream>>>(srci, dsti, ea, basemat,
                                           tmp_meta, tmp_ea, E, nbins, chunk);
    pass2_kernel<<<nbins, 256, 0, stream>>>(binstart, tmp_meta, tmp_ea,
                                            rowstart, src_sorted, ea_sorted,
                                            N, E);

    // ---- Layers (wave-per-node, bf16 ea; bf16 h chain) ----
    const int lblocks = (N + 15) / 16;
    gine_layer_wave<32, 8, 8, false><<<lblocks, 256, 0, stream>>>(
        x, rowstart, src_sorted, ea_sorted,
        (const float*)d_in[3], (const float*)d_in[4],
        (const float*)d_in[5], (const float*)d_in[6],
        (const float*)d_in[7], (const float*)d_in[8],
        (const float*)d_in[9], (const float*)d_in[10],
        (const float*)d_in[11], (const float*)d_in[12], h1, N);

    gine_layer_wave<16, 4, 16, true><<<lblocks, 256, 0, stream>>>(
        h1, rowstart, src_sorted, ea_sorted,
        (const float*)d_in[13], (const float*)d_in[14],
        (const float*)d_in[15], (const float*)d_in[16],
        (const float*)d_in[17], (const float*)d_in[18],
        (const float*)d_in[19], (const float*)d_in[20],
        (const float*)d_in[21], (const float*)d_in[22], h2, N);

    gine_layer_wave<16, 4, 16, true><<<lblocks, 256, 0, stream>>>(
        h2, rowstart, src_sorted, ea_sorted,
        (const float*)d_in[23], (const float*)d_in[24],
        (const float*)d_in[25], (const float*)d_in[26],
        (const float*)d_in[27], (const float*)d_in[28],
        (const float*)d_in[29], (const float*)d_in[30],
        (const float*)d_in[31], (const float*)d_in[32], h3, N);

    // ---- Head ----
    final_kernel<<<(N + 63) / 64, 256, 0, stream>>>(
        h1, h2, h3, lw1, lb1, lw2, lb2, (float*)d_out, N);
}